// Round 11
// baseline (320.480 us; speedup 1.0000x reference)
//
#include <hip/hip_runtime.h>
#include <hip/hip_fp16.h>
#include <stdint.h>

static constexpr int CI = 16;
static constexpr int CO = 32;
static constexpr int H  = 300000;
static constexpr int K  = 27;
static constexpr float BN_EPS = 1e-5f;

// ---------- f16 helpers ----------
typedef _Float16 h2_t __attribute__((ext_vector_type(2)));

__device__ __forceinline__ unsigned int pack_f16(float lo, float hi) {
    union { h2_t h; unsigned int u; } v;
    v.h[0] = (_Float16)lo;
    v.h[1] = (_Float16)hi;
    return v.u;
}

// acc += a.lo*b.lo + a.hi*b.hi  (v_dot2_f32_f16)
__device__ __forceinline__ float dot2f(unsigned int a, unsigned int b, float c) {
#if __has_builtin(__builtin_amdgcn_fdot2)
    union { unsigned int u; h2_t h; } ua, ub;
    ua.u = a; ub.u = b;
    return __builtin_amdgcn_fdot2(ua.h, ub.h, c, false);
#else
    union { unsigned int u; h2_t h; } ua, ub;
    ua.u = a; ub.u = b;
    float r = fmaf((float)ua.h[0], (float)ub.h[0], c);
    return fmaf((float)ua.h[1], (float)ub.h[1], r);
#endif
}

// ---------- kernel 1: fused prep ----------
__global__ __launch_bounds__(256) void prep(const float* __restrict__ x,
                                            const float* __restrict__ w,
                                            unsigned int* __restrict__ xTp,
                                            unsigned int* __restrict__ wp,
                                            float* __restrict__ stats) {
    int h = blockIdx.x * 256 + threadIdx.x;
    if (h < H) {
        unsigned int r[8];
        #pragma unroll
        for (int j = 0; j < 8; ++j)
            r[j] = pack_f16(x[(size_t)(2 * j) * H + h], x[(size_t)(2 * j + 1) * H + h]);
        uint4* dst = reinterpret_cast<uint4*>(xTp + (size_t)h * 8);
        dst[0] = make_uint4(r[0], r[1], r[2], r[3]);
        dst[1] = make_uint4(r[4], r[5], r[6], r[7]);
    }
    if (blockIdx.x == 0) {
        for (int idx = threadIdx.x; idx < K * CO * 8; idx += 256) {
            int j = idx & 7;
            int o = (idx >> 3) & 31;
            int k = idx >> 8;
            float lo = w[((size_t)o * CI + 2 * j) * K + k];
            float hi = w[((size_t)o * CI + 2 * j + 1) * K + k];
            wp[idx] = pack_f16(lo, hi);
        }
        if (threadIdx.x < 64) stats[threadIdx.x] = 0.f;   // gsum[32] ++ gsq[32]
    }
}

// ---------- kernel 2: gathered conv (f16 dot2), 2-deep pipeline, + BN stats ----------
// Block: 256 threads = 128 h. t<128 -> outputs 0-15, t>=128 -> outputs 16-31.
// 2-deep gather pipeline: rows for k+1 and k+2 in flight while computing k
// (4 outstanding dwordx4/thread) — attacks the ~500cy L3-hit latency that
// capped R10 at 35% VALUBusy / 2 TB/s fill.
__global__ __launch_bounds__(256, 6) void conv(const unsigned int* __restrict__ xTp,
                                               const unsigned int* __restrict__ wp,
                                               const int* __restrict__ neigh,
                                               float* __restrict__ out,
                                               float* __restrict__ stats) {
    __shared__ int snb[128 * K];
    const int t    = threadIdx.x;
    const int hl   = t & 127;
    const int half = __builtin_amdgcn_readfirstlane(t >> 7);   // wave-uniform 0/1
    const int h    = blockIdx.x * 128 + hl;

    // stage this block's neighbor indices coalesced into LDS (nontemporal stream)
    {
        const int base = blockIdx.x * 128 * K;
        for (int s = t; s < 128 * K; s += 256) {
            int g = base + s;
            snb[s] = (g < H * K) ? __builtin_nontemporal_load(&neigh[g]) : -1;
        }
    }
    __syncthreads();

    float acc[16];
    #pragma unroll
    for (int o = 0; o < 16; ++o) acc[o] = 0.f;

    if (h < H) {
        const int* np = &snb[hl * K];
        const unsigned int* wh = wp + half * 128;   // this half's 16 outputs x 8 pairs

        // prologue: prefetch k = 0 and k = 1
        int idx0 = np[0];
        const uint4* q0 = reinterpret_cast<const uint4*>(
            xTp + (size_t)(idx0 < 0 ? 0 : idx0) * 8);
        uint4 a0 = q0[0];
        uint4 b0 = q0[1];

        int idx1 = (K > 1) ? np[1] : 0;
        const uint4* q1 = reinterpret_cast<const uint4*>(
            xTp + (size_t)(idx1 < 0 ? 0 : idx1) * 8);
        uint4 a1 = q1[0];
        uint4 b1 = q1[1];

        for (int k = 0; k < K; ++k) {
            // issue gather for k+2 (2-deep)
            int idx2 = (k + 2 < K) ? np[k + 2] : 0;
            const uint4* q2 = reinterpret_cast<const uint4*>(
                xTp + (size_t)(idx2 < 0 ? 0 : idx2) * 8);
            uint4 a2 = q2[0];
            uint4 b2 = q2[1];

            if (idx0 < 0) {                     // cndmask zero for invalid neighbor
                a0.x = a0.y = a0.z = a0.w = 0u;
                b0.x = b0.y = b0.z = b0.w = 0u;
            }

            const unsigned int* wk = wh + k * 256;   // wave-uniform -> scalar loads
            #pragma unroll
            for (int o = 0; o < 16; ++o) {
                float s = acc[o];
                s = dot2f(a0.x, wk[o * 8 + 0], s);
                s = dot2f(a0.y, wk[o * 8 + 1], s);
                s = dot2f(a0.z, wk[o * 8 + 2], s);
                s = dot2f(a0.w, wk[o * 8 + 3], s);
                s = dot2f(b0.x, wk[o * 8 + 4], s);
                s = dot2f(b0.y, wk[o * 8 + 5], s);
                s = dot2f(b0.z, wk[o * 8 + 6], s);
                s = dot2f(b0.w, wk[o * 8 + 7], s);
                acc[o] = s;
            }

            idx0 = idx1; a0 = a1; b0 = b1;
            idx1 = idx2; a1 = a2; b1 = b2;
        }
        #pragma unroll
        for (int o = 0; o < 16; ++o)
            out[(size_t)(half * 16 + o) * H + h] = acc[o];   // coalesced over h
    }

    // fused BN statistics: butterfly per output, one atomic per wave per output
    const unsigned lane = t & 63u;
    float mySum = 0.f, mySq = 0.f;
    #pragma unroll
    for (int o = 0; o < 16; ++o) {
        float v = acc[o];
        float q = v * v;
        #pragma unroll
        for (int d = 32; d > 0; d >>= 1) {
            v += __shfl_xor(v, d, 64);
            q += __shfl_xor(q, d, 64);
        }
        if (lane == (unsigned)o) { mySum = v; mySq = q; }
    }
    if (lane < 16u) {
        atomicAdd(&stats[half * 16 + lane], mySum);        // gsum
        atomicAdd(&stats[32 + half * 16 + lane], mySq);    // gsq
    }
}

// ---------- kernel 3: BN apply (scale/shift recomputed per thread from stats) ----------
__global__ __launch_bounds__(256) void bn_apply(float* __restrict__ out,
                                                const float* __restrict__ stats,
                                                const float* __restrict__ gamma,
                                                const float* __restrict__ beta) {
    size_t t = (size_t)blockIdx.x * 256 + threadIdx.x;
    size_t base = t * 4;
    if (base >= (size_t)CO * H) return;
    int o = (int)(base / (size_t)H);     // H % 4 == 0 -> float4 never crosses channels
    const float invH = 1.f / (float)H;
    float m   = stats[o] * invH;
    float var = stats[32 + o] * invH - m * m;
    float inv = rsqrtf(var + BN_EPS);
    float sc  = gamma[o] * inv;
    float sh  = beta[o] - m * sc;
    float4* p = reinterpret_cast<float4*>(out + base);
    float4 q = *p;
    q.x = q.x * sc + sh;
    q.y = q.y * sc + sh;
    q.z = q.z * sc + sh;
    q.w = q.w * sc + sh;
    *p = q;
}

// ---------- launch ----------
extern "C" void kernel_launch(void* const* d_in, const int* in_sizes, int n_in,
                              void* d_out, int out_size, void* d_ws, size_t ws_size,
                              hipStream_t stream) {
    const float* x     = (const float*)d_in[0];   // fp32 (1,CI,H,1)
    const float* w     = (const float*)d_in[1];   // fp32 (CO,CI,K)
    const float* gamma = (const float*)d_in[2];   // fp32 (CO)
    const float* beta  = (const float*)d_in[3];   // fp32 (CO)
    const int*   neigh = (const int*)d_in[4];     // int32 (H,K)
    float*       out   = (float*)d_out;           // fp32 (CO,H)

    char* ws = (char*)d_ws;
    const size_t XT_OFF    = 0;                    // H*8*4   = 9,600,000 B
    const size_t WP_OFF    = 9600000;              // 6912*4  = 27,648 B
    const size_t STATS_OFF = 9627648;              // 64 floats
    unsigned int* xTp   = (unsigned int*)(ws + XT_OFF);
    unsigned int* wp    = (unsigned int*)(ws + WP_OFF);
    float*        stats = (float*)(ws + STATS_OFF);

    const int HBP = (H + 255) / 256;               // 1172 (prep)
    prep<<<HBP, 256, 0, stream>>>(x, w, xTp, wp, stats);

    const int HBC = (H + 127) / 128;               // 2344 (conv: 128 h/block)
    conv<<<HBC, 256, 0, stream>>>(xTp, wp, neigh, out, stats);

    const int NBN = (CO * H / 4 + 255) / 256;      // 9375
    bn_apply<<<NBN, 256, 0, stream>>>(out, stats, gamma, beta);
}